// Round 4
// baseline (487.726 us; speedup 1.0000x reference)
//
#include <hip/hip_runtime.h>
#include <math.h>

#define B_ 32
#define N_ 1024
#define H_ 256
#define A_ 32
#define O_ 256
#define M_ (B_*N_)      // 32768 particles total
#define EPSF 1e-10f

typedef _Float16 f16;
typedef __attribute__((ext_vector_type(8))) _Float16 f16x8;
typedef __attribute__((ext_vector_type(4))) _Float16 f16x4;
typedef __attribute__((ext_vector_type(2))) _Float16 f16x2;
typedef __attribute__((ext_vector_type(4))) float    f32x4;

__device__ __forceinline__ float gelu_exact(float x){
  return 0.5f * x * (1.0f + erff(x * 0.70710678118654752f));
}
__device__ __forceinline__ float sigm(float x){
  return 1.0f / (1.0f + expf(-x));
}

// ---------------- prep kernel: weight transpose (blocks 0..79) + per-batch
// hoisted action/obs contributions (blocks 80..111) ----------------
__global__ __launch_bounds__(256) void k_prep(
    const float* __restrict__ action, const float* __restrict__ observation,
    const float* __restrict__ Wr, const float* __restrict__ br,
    const float* __restrict__ Wu, const float* __restrict__ bu,
    const float* __restrict__ Wc, const float* __restrict__ bc,
    const float* __restrict__ W0, const float* __restrict__ b0,
    f16* __restrict__ WrT, f16* __restrict__ WuT, f16* __restrict__ WcT,
    f16* __restrict__ W0T, f16* __restrict__ W1T, const float* __restrict__ W1,
    float* __restrict__ actR, float* __restrict__ actU,
    float* __restrict__ actC, float* __restrict__ obs0)
{
  const int blk = blockIdx.x;
  if (blk < 80) {
    __shared__ float tile[64][65];
    const int mat = blk >> 4;
    const int kb  = ((blk & 15) >> 2) * 64;
    const int nb  = (blk & 3) * 64;
    const float* W; f16* WT;
    switch (mat) {
      case 0: W = Wr; WT = WrT; break;
      case 1: W = Wu; WT = WuT; break;
      case 2: W = Wc; WT = WcT; break;
      case 3: W = W0; WT = W0T; break;
      default: W = W1; WT = W1T; break;
    }
    const int t = threadIdx.x;
    const int c = t & 63, r4 = t >> 6;
    #pragma unroll
    for (int i = 0; i < 64; i += 4)
      tile[i + r4][c] = W[(size_t)(kb + i + r4)*H_ + nb + c];
    __syncthreads();
    #pragma unroll
    for (int i = 0; i < 64; i += 4)
      WT[(size_t)(nb + i + r4)*H_ + kb + c] = (f16)tile[c][i + r4];
  } else {
    const int b = blk - 80, j = threadIdx.x;
    float aR = br[j], aU = bu[j], aC = bc[j];
    for (int a = 0; a < A_; ++a) {
      float av = action[b*A_ + a];
      aR = fmaf(av, Wr[(H_+a)*H_ + j], aR);
      aU = fmaf(av, Wu[(H_+a)*H_ + j], aU);
      aC = fmaf(av, Wc[(H_+a)*H_ + j], aC);
    }
    float o0 = b0[j];
    for (int o = 0; o < O_; ++o)
      o0 = fmaf(observation[b*O_ + o], W0[(H_+o)*H_ + j], o0);
    actR[b*H_+j] = aR; actU[b*H_+j] = aU; actC[b*H_+j] = aC; obs0[b*H_+j] = o0;
  }
}

// swizzled LDS helpers (64 x 256 fp16 tile, row stride 512 B, XOR (row&7)<<4)
__device__ __forceinline__ f16x8 lda(const unsigned char* xs, int m, int kt,
                                     int lr, int lg) {
  int row = m*16 + lr;
  int off = (row*512 + kt*64 + lg*16) ^ ((row&7)<<4);
  return *(const f16x8*)(xs + off);
}
__device__ __forceinline__ f16 xs_r16(const unsigned char* xs, int row, int col) {
  int off = (row*512 + col*2) ^ ((row&7)<<4);
  return *(const f16*)(xs + off);
}
__device__ __forceinline__ void xs_w16(unsigned char* xs, int row, int col, f16 v) {
  int off = (row*512 + col*2) ^ ((row&7)<<4);
  *(f16*)(xs + off) = v;
}

// one 64x64x256 wave-GEMM: acc += xs(64x256) @ Wt^T-slice (cols colbase..+64)
__device__ __forceinline__ void gemm256(const unsigned char* xs, const f16* __restrict__ Wt,
                                        int lr, int lg, int colbase,
                                        f32x4 acc[4][4]) {
  for (int kt = 0; kt < 8; ++kt) {
    f16x8 a[4], bb[4];
    #pragma unroll
    for (int m = 0; m < 4; ++m) a[m] = lda(xs, m, kt, lr, lg);
    #pragma unroll
    for (int n = 0; n < 4; ++n)
      bb[n] = *(const f16x8*)(Wt + (size_t)(colbase + n*16 + lr)*H_ + kt*32 + lg*8);
    #pragma unroll
    for (int m = 0; m < 4; ++m)
      #pragma unroll
      for (int n = 0; n < 4; ++n)
        acc[m][n] = __builtin_amdgcn_mfma_f32_16x16x32_f16(a[m], bb[n], acc[m][n], 0, 0, 0);
  }
}

// ---------------- kernel 1: fused GRU + MLP (MFMA fp16) ----------------
// 64 particles per block, 4 waves; wave w owns output cols [w*64, w*64+64).
__global__ __launch_bounds__(256, 3) void k_gru_mlp(
    const float* __restrict__ particles, const float* __restrict__ weights,
    const f16* __restrict__ WrT, const f16* __restrict__ WuT,
    const f16* __restrict__ WcT, const f16* __restrict__ W0T,
    const f16* __restrict__ W1T,
    const float* __restrict__ W2, const float* __restrict__ b1v,
    const float* __restrict__ b2v,
    const float* __restrict__ actR, const float* __restrict__ actU,
    const float* __restrict__ actC, const float* __restrict__ obs0,
    f16* __restrict__ ws_nxt16, float* __restrict__ log_w)
{
  __shared__ __align__(16) unsigned char xs[64*512];   // 64 x 256 fp16, swizzled
  __shared__ float red[4][64];

  const int b    = blockIdx.x >> 4;
  const int n0   = (blockIdx.x & 15) << 6;
  const int tid  = threadIdx.x;
  const int w    = tid >> 6;
  const int lane = tid & 63;
  const int lr   = lane & 15;
  const int lg   = lane >> 4;
  const int colbase = w << 6;
  const float* Pbase = particles + (size_t)(b*N_ + n0) * H_;

  int colv[4];
  #pragma unroll
  for (int n = 0; n < 4; ++n) colv[n] = colbase + n*16 + lr;

  // ---- stage particles -> LDS fp16 (swizzled); ONLY global read of P ----
  #pragma unroll
  for (int i = 0; i < 8; ++i) {
    int s = tid + i*256;
    int row = s >> 5, ks = s & 31;
    const float* src = Pbase + row*H_ + ks*8;
    float4 v0 = *(const float4*)src;
    float4 v1 = *(const float4*)(src + 4);
    f16x8 h;
    h[0]=(f16)v0.x; h[1]=(f16)v0.y; h[2]=(f16)v0.z; h[3]=(f16)v0.w;
    h[4]=(f16)v1.x; h[5]=(f16)v1.y; h[6]=(f16)v1.z; h[7]=(f16)v1.w;
    int off = (row*512 + ks*16) ^ ((row&7)<<4);
    *(f16x8*)(xs + off) = h;
  }
  __syncthreads();

  // ---- GEMM 1: reset gate ----
  f32x4 aR[4][4];
  #pragma unroll
  for (int m=0;m<4;++m)
    #pragma unroll
    for (int n=0;n<4;++n) aR[m][n] = (f32x4)(0.f);
  gemm256(xs, WrT, lr, lg, colbase, aR);

  // ---- GEMM 2: update gate ----
  f32x4 aU[4][4];
  #pragma unroll
  for (int m=0;m<4;++m)
    #pragma unroll
    for (int n=0;n<4;++n) aU[m][n] = (f32x4)(0.f);
  gemm256(xs, WuT, lr, lg, colbase, aU);

  float vR[4], vU[4];
  #pragma unroll
  for (int n=0;n<4;++n) { vR[n] = actR[b*H_ + colv[n]]; vU[n] = actU[b*H_ + colv[n]]; }

  f16x4 uh[4][4];   // update gate packed fp16
  #pragma unroll
  for (int m=0;m<4;++m)
    #pragma unroll
    for (int n=0;n<4;++n)
      #pragma unroll
      for (int r=0;r<4;++r) {
        aR[m][n][r] = sigm(aR[m][n][r] + vR[n]);
        uh[m][n][r] = (f16)sigm(aU[m][n][r] + vU[n]);
      }

  __syncthreads();   // all waves done reading particle tile

  // ---- x_reset = particles * R -> LDS; keep orig (f16) in registers ----
  f16x4 oh[4][4];
  #pragma unroll
  for (int m=0;m<4;++m)
    #pragma unroll
    for (int n=0;n<4;++n)
      #pragma unroll
      for (int r=0;r<4;++r) {
        int row = m*16 + lg*4 + r;
        f16 o = xs_r16(xs, row, colv[n]);
        oh[m][n][r] = o;
        xs_w16(xs, row, colv[n], (f16)((float)o * aR[m][n][r]));
      }
  __syncthreads();

  // ---- GEMM 3: candidate; nxt blend -> xs ----
  f32x4 aC[4][4];
  #pragma unroll
  for (int m=0;m<4;++m)
    #pragma unroll
    for (int n=0;n<4;++n) aC[m][n] = (f32x4)(0.f);
  gemm256(xs, WcT, lr, lg, colbase, aC);

  float vC[4];
  #pragma unroll
  for (int n=0;n<4;++n) vC[n] = actC[b*H_ + colv[n]];

  __syncthreads();   // GEMM3 reads done before overwriting xs with nxt
  #pragma unroll
  for (int m=0;m<4;++m)
    #pragma unroll
    for (int n=0;n<4;++n)
      #pragma unroll
      for (int r=0;r<4;++r) {
        int row = m*16 + lg*4 + r;
        float cand = tanhf(aC[m][n][r] + vC[n]);
        float orig = (float)oh[m][n][r];
        float nx   = fmaf((float)uh[m][n][r], cand - orig, orig);
        xs_w16(xs, row, colv[n], (f16)nx);
      }
  __syncthreads();

  // ---- coalesced nxt (f16) -> global workspace; overlaps GEMM 4 reads ----
  f16* wsrow = ws_nxt16 + (size_t)(b*N_ + n0) * H_;
  #pragma unroll
  for (int i = 0; i < 8; ++i) {
    int s = tid + i*256;
    int row = s >> 5, c16 = s & 31;
    int off = (row*512 + c16*16) ^ ((row&7)<<4);
    f16x8 v = *(const f16x8*)(xs + off);
    *(f16x8*)(wsrow + row*H_ + c16*8) = v;
  }

  // ---- GEMM 4: z @ W0 (nxt part; obs part hoisted) + GELU ----
  f32x4 a0[4][4];
  #pragma unroll
  for (int m=0;m<4;++m)
    #pragma unroll
    for (int n=0;n<4;++n) a0[m][n] = (f32x4)(0.f);
  gemm256(xs, W0T, lr, lg, colbase, a0);

  float v0b[4];
  #pragma unroll
  for (int n=0;n<4;++n) v0b[n] = obs0[b*H_ + colv[n]];
  #pragma unroll
  for (int m=0;m<4;++m)
    #pragma unroll
    for (int n=0;n<4;++n)
      #pragma unroll
      for (int r=0;r<4;++r)
        a0[m][n][r] = gelu_exact(a0[m][n][r] + v0b[n]);
  __syncthreads();
  #pragma unroll
  for (int m=0;m<4;++m)
    #pragma unroll
    for (int n=0;n<4;++n)
      #pragma unroll
      for (int r=0;r<4;++r)
        xs_w16(xs, m*16 + lg*4 + r, colv[n], (f16)a0[m][n][r]);
  __syncthreads();

  // ---- GEMM 5: h1 @ W1 + GELU; dot with W2; reduce -> log_lik ----
  f32x4 a1[4][4];
  #pragma unroll
  for (int m=0;m<4;++m)
    #pragma unroll
    for (int n=0;n<4;++n) a1[m][n] = (f32x4)(0.f);
  gemm256(xs, W1T, lr, lg, colbase, a1);

  float v1b[4], w2v[4];
  #pragma unroll
  for (int n=0;n<4;++n) { v1b[n] = b1v[colv[n]]; w2v[n] = W2[colv[n]]; }

  float psum[4][4];   // [m][r]
  #pragma unroll
  for (int m=0;m<4;++m)
    #pragma unroll
    for (int r=0;r<4;++r) psum[m][r] = 0.f;
  #pragma unroll
  for (int m=0;m<4;++m)
    #pragma unroll
    for (int n=0;n<4;++n)
      #pragma unroll
      for (int r=0;r<4;++r)
        psum[m][r] = fmaf(gelu_exact(a1[m][n][r] + v1b[n]), w2v[n], psum[m][r]);

  #pragma unroll
  for (int m=0;m<4;++m)
    #pragma unroll
    for (int r=0;r<4;++r) {
      float v = psum[m][r];
      v += __shfl_xor(v, 1); v += __shfl_xor(v, 2);
      v += __shfl_xor(v, 4); v += __shfl_xor(v, 8);
      psum[m][r] = v;
    }
  if (lr == 0) {
    #pragma unroll
    for (int m=0;m<4;++m)
      #pragma unroll
      for (int r=0;r<4;++r)
        red[w][m*16 + lg*4 + r] = psum[m][r];
  }
  __syncthreads();
  if (tid < 64) {
    float ll = red[0][tid] + red[1][tid] + red[2][tid] + red[3][tid] + b2v[0];
    int gi = b*N_ + n0 + tid;
    log_w[gi] = logf(weights[gi] + EPSF) + ll;
  }
}

// ---------------- kernel 2: per-batch softmax / ESS / csum / searchsorted ----
__global__ __launch_bounds__(256) void k_softmax(
    const float* __restrict__ log_w, const float* __restrict__ u_in,
    float* __restrict__ d_new_w, float* __restrict__ d_ess,
    int* __restrict__ ws_idx, float* __restrict__ ws_should)
{
  __shared__ float cs[N_];
  __shared__ float redbuf[4];
  __shared__ float wsum[4];
  const int b = blockIdx.x, t = threadIdx.x;
  const int wave = t >> 6, lane = t & 63;
  const float* lw = log_w + b*N_;

  float v[4];
  float m = -INFINITY;
  #pragma unroll
  for (int q = 0; q < 4; ++q) { v[q] = lw[t*4+q]; m = fmaxf(m, v[q]); }
  for (int off = 32; off >= 1; off >>= 1) m = fmaxf(m, __shfl_xor(m, off));
  if (lane == 0) redbuf[wave] = m;
  __syncthreads();
  m = fmaxf(fmaxf(redbuf[0], redbuf[1]), fmaxf(redbuf[2], redbuf[3]));

  float s4 = 0.f;
  #pragma unroll
  for (int q = 0; q < 4; ++q) { v[q] = expf(v[q] - m); s4 += v[q]; }

  // wave-level inclusive scan of per-thread sums
  float incl = s4;
  #pragma unroll
  for (int off = 1; off < 64; off <<= 1) {
    float t2 = __shfl_up(incl, off);
    if (lane >= off) incl += t2;
  }
  if (lane == 63) wsum[wave] = incl;
  __syncthreads();
  float woff = 0.f;
  #pragma unroll
  for (int ww = 0; ww < 4; ++ww) woff += (ww < wave) ? wsum[ww] : 0.f;
  const float total = wsum[0] + wsum[1] + wsum[2] + wsum[3];
  const float excl  = woff + incl - s4;
  const float inv   = 1.0f / total;

  float run = excl, sq4 = 0.f;
  #pragma unroll
  for (int q = 0; q < 4; ++q) {
    run += v[q];
    cs[t*4+q] = run * inv;
    float wq = v[q] * inv;
    sq4 += wq * wq;
  }
  for (int off = 32; off >= 1; off >>= 1) sq4 += __shfl_xor(sq4, off);
  __syncthreads();          // cs fully written (also covers redbuf reuse)
  if (lane == 0) redbuf[wave] = sq4;
  __syncthreads();
  const float ssq = redbuf[0] + redbuf[1] + redbuf[2] + redbuf[3];
  const float ess = 1.0f / (ssq + EPSF);
  const bool should = ess < (0.5f * (float)N_);
  if (t == 0) { d_ess[b] = ess; ws_should[b] = should ? 1.0f : 0.0f; }

  const float uw = 1.0f / (float)N_;
  #pragma unroll
  for (int q = 0; q < 4; ++q)
    d_new_w[b*N_ + t*4+q] = should ? uw : v[q] * inv;

  const float ub = u_in[b];
  #pragma unroll
  for (int q = 0; q < 4; ++q) {
    int i = t*4 + q;
    float pos = fminf(ub / (float)N_ + (float)i / (float)N_, 0.9999f);
    int lo = 0, hi = N_;
    while (lo < hi) { int mid = (lo + hi) >> 1; if (cs[mid] < pos) lo = mid + 1; else hi = mid; }
    ws_idx[b*N_ + i] = (lo < N_-1) ? lo : N_-1;
  }
}

// ---------------- kernel 3: resample-select + belief ----------------
// block: 64 rows of one batch; thread t: col-pair (t&127), row-half (t>>7)
__global__ __launch_bounds__(256) void k_final(
    const f16* __restrict__ ws_nxt16, const int* __restrict__ ws_idx,
    const float* __restrict__ ws_should, const float* __restrict__ d_new_w,
    float* __restrict__ d_nxt, float* __restrict__ d_belief)
{
  const int blk = blockIdx.x;
  const int b   = blk >> 4;
  const int n0  = (blk & 15) << 6;
  const int t   = threadIdx.x;
  const int c   = t & 127;          // col pair
  const int hf  = t >> 7;           // row half
  const bool should = ws_should[b] != 0.0f;
  float p0 = 0.f, p1 = 0.f;
  #pragma unroll 4
  for (int r = 0; r < 32; ++r) {
    int n = n0 + hf*32 + r;
    int src = should ? ws_idx[b*N_ + n] : n;
    f16x2 v = *(const f16x2*)(ws_nxt16 + (size_t)(b*N_ + src)*H_ + c*2);
    float w = d_new_w[b*N_ + n];
    float2 st; st.x = (float)v[0]; st.y = (float)v[1];
    *(float2*)(d_nxt + (size_t)(b*N_ + n)*H_ + c*2) = st;
    p0 = fmaf(st.x, w, p0); p1 = fmaf(st.y, w, p1);
  }
  atomicAdd(&d_belief[b*H_ + c*2],     p0);
  atomicAdd(&d_belief[b*H_ + c*2 + 1], p1);
}

// ---------------- launch ----------------
extern "C" void kernel_launch(void* const* d_in, const int* in_sizes, int n_in,
                              void* d_out, int out_size, void* d_ws, size_t ws_size,
                              hipStream_t stream) {
  (void)in_sizes; (void)n_in; (void)out_size; (void)ws_size;
  const float* particles   = (const float*)d_in[0];
  const float* weights     = (const float*)d_in[1];
  const float* action      = (const float*)d_in[2];
  const float* observation = (const float*)d_in[3];
  const float* u_in        = (const float*)d_in[4];
  const float* Wr = (const float*)d_in[5];
  const float* br = (const float*)d_in[6];
  const float* Wu = (const float*)d_in[7];
  const float* bu = (const float*)d_in[8];
  const float* Wc = (const float*)d_in[9];
  const float* bc = (const float*)d_in[10];
  const float* W0 = (const float*)d_in[11];
  const float* b0 = (const float*)d_in[12];
  const float* W1 = (const float*)d_in[13];
  const float* b1 = (const float*)d_in[14];
  const float* W2 = (const float*)d_in[15];
  const float* b2 = (const float*)d_in[16];

  float* out      = (float*)d_out;
  float* d_belief = out;                                  // [B,H]
  float* d_nxt    = out + (size_t)B_*H_;                  // [B,N,H]
  float* d_new_w  = d_nxt + (size_t)M_*H_;                // [B,N]
  float* d_ess    = d_new_w + M_;                         // [B]

  unsigned char* wsb = (unsigned char*)d_ws;
  f16* WrT = (f16*)wsb;                                   // 5 x 256x256 fp16
  f16* WuT = WrT + H_*H_;
  f16* WcT = WuT + H_*H_;
  f16* W0T = WcT + H_*H_;
  f16* W1T = W0T + H_*H_;
  f16* ws_nxt16   = W1T + H_*H_;                          // [M,H] f16, 16 MB
  float* ws_logw  = (float*)(ws_nxt16 + (size_t)M_*H_);   // [M]
  float* ws_actR  = ws_logw + M_;                         // [B,H] x4
  float* ws_actU  = ws_actR + B_*H_;
  float* ws_actC  = ws_actU + B_*H_;
  float* ws_obs0  = ws_actC + B_*H_;
  int*   ws_idx   = (int*)(ws_obs0 + B_*H_);              // [B,N]
  float* ws_should= (float*)(ws_idx + M_);                // [B]

  hipMemsetAsync(d_belief, 0, (size_t)B_*H_*sizeof(float), stream);

  k_prep<<<dim3(112), dim3(256), 0, stream>>>(
      action, observation, Wr, br, Wu, bu, Wc, bc, W0, b0,
      WrT, WuT, WcT, W0T, W1T, W1,
      ws_actR, ws_actU, ws_actC, ws_obs0);

  k_gru_mlp<<<dim3(M_/64), dim3(256), 0, stream>>>(
      particles, weights, WrT, WuT, WcT, W0T, W1T, W2, b1, b2,
      ws_actR, ws_actU, ws_actC, ws_obs0, ws_nxt16, ws_logw);

  k_softmax<<<dim3(B_), dim3(256), 0, stream>>>(
      ws_logw, u_in, d_new_w, d_ess, ws_idx, ws_should);

  k_final<<<dim3(M_/64), dim3(256), 0, stream>>>(
      ws_nxt16, ws_idx, ws_should, d_new_w, d_nxt, d_belief);
}

// Round 6
// 270.248 us; speedup vs baseline: 1.8047x; 1.8047x over previous
//
#include <hip/hip_runtime.h>
#include <math.h>

#define B_ 32
#define N_ 1024
#define H_ 256
#define A_ 32
#define O_ 256
#define M_ (B_*N_)      // 32768 particles total
#define EPSF 1e-10f

typedef _Float16 f16;
typedef __attribute__((ext_vector_type(8))) _Float16 f16x8;
typedef __attribute__((ext_vector_type(4))) _Float16 f16x4;
typedef __attribute__((ext_vector_type(2))) _Float16 f16x2;
typedef __attribute__((ext_vector_type(4))) float    f32x4;

__device__ __forceinline__ float gelu_exact(float x){
  return 0.5f * x * (1.0f + erff(x * 0.70710678118654752f));
}
__device__ __forceinline__ float sigm(float x){
  return 1.0f / (1.0f + expf(-x));
}

// ---------------- prep kernel: weight transpose (blocks 0..79) + per-batch
// hoisted action/obs contributions (blocks 80..111) ----------------
__global__ __launch_bounds__(256) void k_prep(
    const float* __restrict__ action, const float* __restrict__ observation,
    const float* __restrict__ Wr, const float* __restrict__ br,
    const float* __restrict__ Wu, const float* __restrict__ bu,
    const float* __restrict__ Wc, const float* __restrict__ bc,
    const float* __restrict__ W0, const float* __restrict__ b0,
    f16* __restrict__ WrT, f16* __restrict__ WuT, f16* __restrict__ WcT,
    f16* __restrict__ W0T, f16* __restrict__ W1T, const float* __restrict__ W1,
    float* __restrict__ actR, float* __restrict__ actU,
    float* __restrict__ actC, float* __restrict__ obs0)
{
  const int blk = blockIdx.x;
  if (blk < 80) {
    __shared__ float tile[64][65];
    const int mat = blk >> 4;
    const int kb  = ((blk & 15) >> 2) * 64;
    const int nb  = (blk & 3) * 64;
    const float* W; f16* WT;
    switch (mat) {
      case 0: W = Wr; WT = WrT; break;
      case 1: W = Wu; WT = WuT; break;
      case 2: W = Wc; WT = WcT; break;
      case 3: W = W0; WT = W0T; break;
      default: W = W1; WT = W1T; break;
    }
    const int t = threadIdx.x;
    const int c = t & 63, r4 = t >> 6;
    #pragma unroll
    for (int i = 0; i < 64; i += 4)
      tile[i + r4][c] = W[(size_t)(kb + i + r4)*H_ + nb + c];
    __syncthreads();
    #pragma unroll
    for (int i = 0; i < 64; i += 4)
      WT[(size_t)(nb + i + r4)*H_ + kb + c] = (f16)tile[c][i + r4];
  } else {
    const int b = blk - 80, j = threadIdx.x;
    float aR = br[j], aU = bu[j], aC = bc[j];
    for (int a = 0; a < A_; ++a) {
      float av = action[b*A_ + a];
      aR = fmaf(av, Wr[(H_+a)*H_ + j], aR);
      aU = fmaf(av, Wu[(H_+a)*H_ + j], aU);
      aC = fmaf(av, Wc[(H_+a)*H_ + j], aC);
    }
    float o0 = b0[j];
    for (int o = 0; o < O_; ++o)
      o0 = fmaf(observation[b*O_ + o], W0[(H_+o)*H_ + j], o0);
    actR[b*H_+j] = aR; actU[b*H_+j] = aU; actC[b*H_+j] = aC; obs0[b*H_+j] = o0;
  }
}

// swizzled LDS helpers (64 x 256 fp16 tile, row stride 512 B, XOR (row&7)<<4)
__device__ __forceinline__ f16x8 lda(const unsigned char* xs, int m, int kt,
                                     int lr, int lg) {
  int row = m*16 + lr;
  int off = (row*512 + kt*64 + lg*16) ^ ((row&7)<<4);
  return *(const f16x8*)(xs + off);
}
__device__ __forceinline__ f16 xs_r16(const unsigned char* xs, int row, int col) {
  int off = (row*512 + col*2) ^ ((row&7)<<4);
  return *(const f16*)(xs + off);
}
__device__ __forceinline__ void xs_w16(unsigned char* xs, int row, int col, f16 v) {
  int off = (row*512 + col*2) ^ ((row&7)<<4);
  *(f16*)(xs + off) = v;
}

// one 64x64x256 wave-GEMM: acc += xs(64x256) @ Wt^T-slice (cols colbase..+64)
// B-fragment loaded inside the n-loop to cap live fragment registers.
__device__ __forceinline__ void gemm256(const unsigned char* xs, const f16* __restrict__ Wt,
                                        int lr, int lg, int colbase,
                                        f32x4 acc[4][4]) {
  for (int kt = 0; kt < 8; ++kt) {
    f16x8 a[4];
    #pragma unroll
    for (int m = 0; m < 4; ++m) a[m] = lda(xs, m, kt, lr, lg);
    #pragma unroll
    for (int n = 0; n < 4; ++n) {
      f16x8 bb = *(const f16x8*)(Wt + (size_t)(colbase + n*16 + lr)*H_ + kt*32 + lg*8);
      #pragma unroll
      for (int m = 0; m < 4; ++m)
        acc[m][n] = __builtin_amdgcn_mfma_f32_16x16x32_f16(a[m], bb, acc[m][n], 0, 0, 0);
    }
  }
}

// ---------------- kernel 1: fused GRU + MLP (MFMA fp16) ----------------
// 64 particles per block, 4 waves; wave w owns output cols [w*64, w*64+64).
__global__ __launch_bounds__(256, 2) void k_gru_mlp(
    const float* __restrict__ particles, const float* __restrict__ weights,
    const f16* __restrict__ WrT, const f16* __restrict__ WuT,
    const f16* __restrict__ WcT, const f16* __restrict__ W0T,
    const f16* __restrict__ W1T,
    const float* __restrict__ W2, const float* __restrict__ b1v,
    const float* __restrict__ b2v,
    const float* __restrict__ actR, const float* __restrict__ actU,
    const float* __restrict__ actC, const float* __restrict__ obs0,
    f16* __restrict__ ws_nxt16, float* __restrict__ log_w)
{
  __shared__ __align__(16) unsigned char xs[64*512];   // 64 x 256 fp16, swizzled
  __shared__ float red[4][64];

  const int b    = blockIdx.x >> 4;
  const int n0   = (blockIdx.x & 15) << 6;
  const int tid  = threadIdx.x;
  const int w    = tid >> 6;
  const int lane = tid & 63;
  const int lr   = lane & 15;
  const int lg   = lane >> 4;
  const int colbase = w << 6;
  const float* Pbase = particles + (size_t)(b*N_ + n0) * H_;

  int colv[4];
  #pragma unroll
  for (int n = 0; n < 4; ++n) colv[n] = colbase + n*16 + lr;

  // ---- stage particles -> LDS fp16 (swizzled); ONLY global read of P ----
  #pragma unroll
  for (int i = 0; i < 8; ++i) {
    int s = tid + i*256;
    int row = s >> 5, ks = s & 31;
    const float* src = Pbase + row*H_ + ks*8;
    float4 v0 = *(const float4*)src;
    float4 v1 = *(const float4*)(src + 4);
    f16x8 h;
    h[0]=(f16)v0.x; h[1]=(f16)v0.y; h[2]=(f16)v0.z; h[3]=(f16)v0.w;
    h[4]=(f16)v1.x; h[5]=(f16)v1.y; h[6]=(f16)v1.z; h[7]=(f16)v1.w;
    int off = (row*512 + ks*16) ^ ((row&7)<<4);
    *(f16x8*)(xs + off) = h;
  }
  __syncthreads();

  // ---- GEMM 1: reset gate ----
  f32x4 aR[4][4];
  #pragma unroll
  for (int m=0;m<4;++m)
    #pragma unroll
    for (int n=0;n<4;++n) aR[m][n] = (f32x4)(0.f);
  gemm256(xs, WrT, lr, lg, colbase, aR);

  // ---- GEMM 2: update gate ----
  f32x4 aU[4][4];
  #pragma unroll
  for (int m=0;m<4;++m)
    #pragma unroll
    for (int n=0;n<4;++n) aU[m][n] = (f32x4)(0.f);
  gemm256(xs, WuT, lr, lg, colbase, aU);

  float vR[4], vU[4];
  #pragma unroll
  for (int n=0;n<4;++n) { vR[n] = actR[b*H_ + colv[n]]; vU[n] = actU[b*H_ + colv[n]]; }

  f16x4 uh[4][4];   // update gate packed fp16
  #pragma unroll
  for (int m=0;m<4;++m)
    #pragma unroll
    for (int n=0;n<4;++n)
      #pragma unroll
      for (int r=0;r<4;++r) {
        aR[m][n][r] = sigm(aR[m][n][r] + vR[n]);
        uh[m][n][r] = (f16)sigm(aU[m][n][r] + vU[n]);
      }

  __syncthreads();   // all waves done reading particle tile

  // ---- x_reset = particles * R -> LDS; keep orig (f16) in registers ----
  f16x4 oh[4][4];
  #pragma unroll
  for (int m=0;m<4;++m)
    #pragma unroll
    for (int n=0;n<4;++n)
      #pragma unroll
      for (int r=0;r<4;++r) {
        int row = m*16 + lg*4 + r;
        f16 o = xs_r16(xs, row, colv[n]);
        oh[m][n][r] = o;
        xs_w16(xs, row, colv[n], (f16)((float)o * aR[m][n][r]));
      }
  __syncthreads();

  // ---- GEMM 3: candidate; nxt blend -> xs ----
  f32x4 aC[4][4];
  #pragma unroll
  for (int m=0;m<4;++m)
    #pragma unroll
    for (int n=0;n<4;++n) aC[m][n] = (f32x4)(0.f);
  gemm256(xs, WcT, lr, lg, colbase, aC);

  float vC[4];
  #pragma unroll
  for (int n=0;n<4;++n) vC[n] = actC[b*H_ + colv[n]];

  __syncthreads();   // GEMM3 reads done before overwriting xs with nxt
  #pragma unroll
  for (int m=0;m<4;++m)
    #pragma unroll
    for (int n=0;n<4;++n)
      #pragma unroll
      for (int r=0;r<4;++r) {
        int row = m*16 + lg*4 + r;
        float cand = tanhf(aC[m][n][r] + vC[n]);
        float orig = (float)oh[m][n][r];
        float nx   = fmaf((float)uh[m][n][r], cand - orig, orig);
        xs_w16(xs, row, colv[n], (f16)nx);
      }
  __syncthreads();

  // ---- coalesced nxt (f16) -> global workspace; overlaps GEMM 4 reads ----
  f16* wsrow = ws_nxt16 + (size_t)(b*N_ + n0) * H_;
  #pragma unroll
  for (int i = 0; i < 8; ++i) {
    int s = tid + i*256;
    int row = s >> 5, c16 = s & 31;
    int off = (row*512 + c16*16) ^ ((row&7)<<4);
    f16x8 v = *(const f16x8*)(xs + off);
    *(f16x8*)(wsrow + row*H_ + c16*8) = v;
  }

  // ---- GEMM 4: z @ W0 (nxt part; obs part hoisted) + GELU ----
  f32x4 a0[4][4];
  #pragma unroll
  for (int m=0;m<4;++m)
    #pragma unroll
    for (int n=0;n<4;++n) a0[m][n] = (f32x4)(0.f);
  gemm256(xs, W0T, lr, lg, colbase, a0);

  float v0b[4];
  #pragma unroll
  for (int n=0;n<4;++n) v0b[n] = obs0[b*H_ + colv[n]];
  #pragma unroll
  for (int m=0;m<4;++m)
    #pragma unroll
    for (int n=0;n<4;++n)
      #pragma unroll
      for (int r=0;r<4;++r)
        a0[m][n][r] = gelu_exact(a0[m][n][r] + v0b[n]);
  __syncthreads();
  #pragma unroll
  for (int m=0;m<4;++m)
    #pragma unroll
    for (int n=0;n<4;++n)
      #pragma unroll
      for (int r=0;r<4;++r)
        xs_w16(xs, m*16 + lg*4 + r, colv[n], (f16)a0[m][n][r]);
  __syncthreads();

  // ---- GEMM 5: h1 @ W1 + GELU; dot with W2; reduce -> log_lik ----
  f32x4 a1[4][4];
  #pragma unroll
  for (int m=0;m<4;++m)
    #pragma unroll
    for (int n=0;n<4;++n) a1[m][n] = (f32x4)(0.f);
  gemm256(xs, W1T, lr, lg, colbase, a1);

  float v1b[4], w2v[4];
  #pragma unroll
  for (int n=0;n<4;++n) { v1b[n] = b1v[colv[n]]; w2v[n] = W2[colv[n]]; }

  float psum[4][4];   // [m][r]
  #pragma unroll
  for (int m=0;m<4;++m)
    #pragma unroll
    for (int r=0;r<4;++r) psum[m][r] = 0.f;
  #pragma unroll
  for (int m=0;m<4;++m)
    #pragma unroll
    for (int n=0;n<4;++n)
      #pragma unroll
      for (int r=0;r<4;++r)
        psum[m][r] = fmaf(gelu_exact(a1[m][n][r] + v1b[n]), w2v[n], psum[m][r]);

  #pragma unroll
  for (int m=0;m<4;++m)
    #pragma unroll
    for (int r=0;r<4;++r) {
      float v = psum[m][r];
      v += __shfl_xor(v, 1); v += __shfl_xor(v, 2);
      v += __shfl_xor(v, 4); v += __shfl_xor(v, 8);
      psum[m][r] = v;
    }
  if (lr == 0) {
    #pragma unroll
    for (int m=0;m<4;++m)
      #pragma unroll
      for (int r=0;r<4;++r)
        red[w][m*16 + lg*4 + r] = psum[m][r];
  }
  __syncthreads();
  if (tid < 64) {
    float ll = red[0][tid] + red[1][tid] + red[2][tid] + red[3][tid] + b2v[0];
    int gi = b*N_ + n0 + tid;
    log_w[gi] = logf(weights[gi] + EPSF) + ll;
  }
}

// ---------------- kernel 2: per-batch softmax / ESS / csum / searchsorted ----
__global__ __launch_bounds__(256) void k_softmax(
    const float* __restrict__ log_w, const float* __restrict__ u_in,
    float* __restrict__ d_new_w, float* __restrict__ d_ess,
    int* __restrict__ ws_idx, float* __restrict__ ws_should)
{
  __shared__ float cs[N_];
  __shared__ float redbuf[4];
  __shared__ float wsum[4];
  const int b = blockIdx.x, t = threadIdx.x;
  const int wave = t >> 6, lane = t & 63;
  const float* lw = log_w + b*N_;

  float v[4];
  float m = -INFINITY;
  #pragma unroll
  for (int q = 0; q < 4; ++q) { v[q] = lw[t*4+q]; m = fmaxf(m, v[q]); }
  for (int off = 32; off >= 1; off >>= 1) m = fmaxf(m, __shfl_xor(m, off));
  if (lane == 0) redbuf[wave] = m;
  __syncthreads();
  m = fmaxf(fmaxf(redbuf[0], redbuf[1]), fmaxf(redbuf[2], redbuf[3]));

  float s4 = 0.f;
  #pragma unroll
  for (int q = 0; q < 4; ++q) { v[q] = expf(v[q] - m); s4 += v[q]; }

  // wave-level inclusive scan of per-thread sums
  float incl = s4;
  #pragma unroll
  for (int off = 1; off < 64; off <<= 1) {
    float t2 = __shfl_up(incl, off);
    if (lane >= off) incl += t2;
  }
  if (lane == 63) wsum[wave] = incl;
  __syncthreads();
  float woff = 0.f;
  #pragma unroll
  for (int ww = 0; ww < 4; ++ww) woff += (ww < wave) ? wsum[ww] : 0.f;
  const float total = wsum[0] + wsum[1] + wsum[2] + wsum[3];
  const float excl  = woff + incl - s4;
  const float inv   = 1.0f / total;

  float run = excl, sq4 = 0.f;
  #pragma unroll
  for (int q = 0; q < 4; ++q) {
    run += v[q];
    cs[t*4+q] = run * inv;
    float wq = v[q] * inv;
    sq4 += wq * wq;
  }
  for (int off = 32; off >= 1; off >>= 1) sq4 += __shfl_xor(sq4, off);
  __syncthreads();          // cs fully written (also covers redbuf reuse)
  if (lane == 0) redbuf[wave] = sq4;
  __syncthreads();
  const float ssq = redbuf[0] + redbuf[1] + redbuf[2] + redbuf[3];
  const float ess = 1.0f / (ssq + EPSF);
  const bool should = ess < (0.5f * (float)N_);
  if (t == 0) { d_ess[b] = ess; ws_should[b] = should ? 1.0f : 0.0f; }

  const float uw = 1.0f / (float)N_;
  #pragma unroll
  for (int q = 0; q < 4; ++q)
    d_new_w[b*N_ + t*4+q] = should ? uw : v[q] * inv;

  const float ub = u_in[b];
  #pragma unroll
  for (int q = 0; q < 4; ++q) {
    int i = t*4 + q;
    float pos = fminf(ub / (float)N_ + (float)i / (float)N_, 0.9999f);
    int lo = 0, hi = N_;
    while (lo < hi) { int mid = (lo + hi) >> 1; if (cs[mid] < pos) lo = mid + 1; else hi = mid; }
    ws_idx[b*N_ + i] = (lo < N_-1) ? lo : N_-1;
  }
}

// ---------------- kernel 3: resample-select + belief ----------------
// block: 64 rows of one batch; thread t: col-pair (t&127), row-half (t>>7)
__global__ __launch_bounds__(256) void k_final(
    const f16* __restrict__ ws_nxt16, const int* __restrict__ ws_idx,
    const float* __restrict__ ws_should, const float* __restrict__ d_new_w,
    float* __restrict__ d_nxt, float* __restrict__ d_belief)
{
  const int blk = blockIdx.x;
  const int b   = blk >> 4;
  const int n0  = (blk & 15) << 6;
  const int t   = threadIdx.x;
  const int c   = t & 127;          // col pair
  const int hf  = t >> 7;           // row half
  const bool should = ws_should[b] != 0.0f;
  float p0 = 0.f, p1 = 0.f;
  #pragma unroll 4
  for (int r = 0; r < 32; ++r) {
    int n = n0 + hf*32 + r;
    int src = should ? ws_idx[b*N_ + n] : n;
    f16x2 v = *(const f16x2*)(ws_nxt16 + (size_t)(b*N_ + src)*H_ + c*2);
    float w = d_new_w[b*N_ + n];
    float2 st; st.x = (float)v[0]; st.y = (float)v[1];
    *(float2*)(d_nxt + (size_t)(b*N_ + n)*H_ + c*2) = st;
    p0 = fmaf(st.x, w, p0); p1 = fmaf(st.y, w, p1);
  }
  atomicAdd(&d_belief[b*H_ + c*2],     p0);
  atomicAdd(&d_belief[b*H_ + c*2 + 1], p1);
}

// ---------------- launch ----------------
extern "C" void kernel_launch(void* const* d_in, const int* in_sizes, int n_in,
                              void* d_out, int out_size, void* d_ws, size_t ws_size,
                              hipStream_t stream) {
  (void)in_sizes; (void)n_in; (void)out_size; (void)ws_size;
  const float* particles   = (const float*)d_in[0];
  const float* weights     = (const float*)d_in[1];
  const float* action      = (const float*)d_in[2];
  const float* observation = (const float*)d_in[3];
  const float* u_in        = (const float*)d_in[4];
  const float* Wr = (const float*)d_in[5];
  const float* br = (const float*)d_in[6];
  const float* Wu = (const float*)d_in[7];
  const float* bu = (const float*)d_in[8];
  const float* Wc = (const float*)d_in[9];
  const float* bc = (const float*)d_in[10];
  const float* W0 = (const float*)d_in[11];
  const float* b0 = (const float*)d_in[12];
  const float* W1 = (const float*)d_in[13];
  const float* b1 = (const float*)d_in[14];
  const float* W2 = (const float*)d_in[15];
  const float* b2 = (const float*)d_in[16];

  float* out      = (float*)d_out;
  float* d_belief = out;                                  // [B,H]
  float* d_nxt    = out + (size_t)B_*H_;                  // [B,N,H]
  float* d_new_w  = d_nxt + (size_t)M_*H_;                // [B,N]
  float* d_ess    = d_new_w + M_;                         // [B]

  unsigned char* wsb = (unsigned char*)d_ws;
  f16* WrT = (f16*)wsb;                                   // 5 x 256x256 fp16
  f16* WuT = WrT + H_*H_;
  f16* WcT = WuT + H_*H_;
  f16* W0T = WcT + H_*H_;
  f16* W1T = W0T + H_*H_;
  f16* ws_nxt16   = W1T + H_*H_;                          // [M,H] f16, 16 MB
  float* ws_logw  = (float*)(ws_nxt16 + (size_t)M_*H_);   // [M]
  float* ws_actR  = ws_logw + M_;                         // [B,H] x4
  float* ws_actU  = ws_actR + B_*H_;
  float* ws_actC  = ws_actU + B_*H_;
  float* ws_obs0  = ws_actC + B_*H_;
  int*   ws_idx   = (int*)(ws_obs0 + B_*H_);              // [B,N]
  float* ws_should= (float*)(ws_idx + M_);                // [B]

  hipMemsetAsync(d_belief, 0, (size_t)B_*H_*sizeof(float), stream);

  k_prep<<<dim3(112), dim3(256), 0, stream>>>(
      action, observation, Wr, br, Wu, bu, Wc, bc, W0, b0,
      WrT, WuT, WcT, W0T, W1T, W1,
      ws_actR, ws_actU, ws_actC, ws_obs0);

  k_gru_mlp<<<dim3(M_/64), dim3(256), 0, stream>>>(
      particles, weights, WrT, WuT, WcT, W0T, W1T, W2, b1, b2,
      ws_actR, ws_actU, ws_actC, ws_obs0, ws_nxt16, ws_logw);

  k_softmax<<<dim3(B_), dim3(256), 0, stream>>>(
      ws_logw, u_in, d_new_w, d_ess, ws_idx, ws_should);

  k_final<<<dim3(M_/64), dim3(256), 0, stream>>>(
      ws_nxt16, ws_idx, ws_should, d_new_w, d_nxt, d_belief);
}

// Round 7
// 230.374 us; speedup vs baseline: 2.1171x; 1.1731x over previous
//
#include <hip/hip_runtime.h>
#include <math.h>

#define B_ 32
#define N_ 1024
#define H_ 256
#define A_ 32
#define O_ 256
#define M_ (B_*N_)      // 32768 particles total
#define EPSF 1e-10f

typedef _Float16 f16;
typedef __attribute__((ext_vector_type(8))) _Float16 f16x8;
typedef __attribute__((ext_vector_type(4))) _Float16 f16x4;
typedef __attribute__((ext_vector_type(2))) _Float16 f16x2;
typedef __attribute__((ext_vector_type(4))) float    f32x4;

__device__ __forceinline__ float gelu_exact(float x){
  return 0.5f * x * (1.0f + erff(x * 0.70710678118654752f));
}
__device__ __forceinline__ float sigm(float x){
  return 1.0f / (1.0f + expf(-x));
}

// ---------------- prep kernel: weight transpose (blocks 0..79) + per-batch
// hoisted action/obs contributions (blocks 80..111) ----------------
__global__ __launch_bounds__(256) void k_prep(
    const float* __restrict__ action, const float* __restrict__ observation,
    const float* __restrict__ Wr, const float* __restrict__ br,
    const float* __restrict__ Wu, const float* __restrict__ bu,
    const float* __restrict__ Wc, const float* __restrict__ bc,
    const float* __restrict__ W0, const float* __restrict__ b0,
    f16* __restrict__ WrT, f16* __restrict__ WuT, f16* __restrict__ WcT,
    f16* __restrict__ W0T, f16* __restrict__ W1T, const float* __restrict__ W1,
    float* __restrict__ actR, float* __restrict__ actU,
    float* __restrict__ actC, float* __restrict__ obs0)
{
  const int blk = blockIdx.x;
  if (blk < 80) {
    __shared__ float tile[64][65];
    const int mat = blk >> 4;
    const int kb  = ((blk & 15) >> 2) * 64;
    const int nb  = (blk & 3) * 64;
    const float* W; f16* WT;
    switch (mat) {
      case 0: W = Wr; WT = WrT; break;
      case 1: W = Wu; WT = WuT; break;
      case 2: W = Wc; WT = WcT; break;
      case 3: W = W0; WT = W0T; break;
      default: W = W1; WT = W1T; break;
    }
    const int t = threadIdx.x;
    const int c = t & 63, r4 = t >> 6;
    #pragma unroll
    for (int i = 0; i < 64; i += 4)
      tile[i + r4][c] = W[(size_t)(kb + i + r4)*H_ + nb + c];
    __syncthreads();
    #pragma unroll
    for (int i = 0; i < 64; i += 4)
      WT[(size_t)(nb + i + r4)*H_ + kb + c] = (f16)tile[c][i + r4];
  } else {
    const int b = blk - 80, j = threadIdx.x;
    float aR = br[j], aU = bu[j], aC = bc[j];
    for (int a = 0; a < A_; ++a) {
      float av = action[b*A_ + a];
      aR = fmaf(av, Wr[(H_+a)*H_ + j], aR);
      aU = fmaf(av, Wu[(H_+a)*H_ + j], aU);
      aC = fmaf(av, Wc[(H_+a)*H_ + j], aC);
    }
    float o0 = b0[j];
    for (int o = 0; o < O_; ++o)
      o0 = fmaf(observation[b*O_ + o], W0[(H_+o)*H_ + j], o0);
    actR[b*H_+j] = aR; actU[b*H_+j] = aU; actC[b*H_+j] = aC; obs0[b*H_+j] = o0;
  }
}

// swizzled LDS helpers (64 x 256 fp16 tile, row stride 512 B, XOR (row&7)<<4)
__device__ __forceinline__ f16x8 lda(const unsigned char* xs, int m, int kt,
                                     int lr, int lg) {
  int row = m*16 + lr;
  int off = (row*512 + kt*64 + lg*16) ^ ((row&7)<<4);
  return *(const f16x8*)(xs + off);
}
__device__ __forceinline__ f16 xs_r16(const unsigned char* xs, int row, int col) {
  int off = (row*512 + col*2) ^ ((row&7)<<4);
  return *(const f16*)(xs + off);
}
__device__ __forceinline__ void xs_w16(unsigned char* xs, int row, int col, f16 v) {
  int off = (row*512 + col*2) ^ ((row&7)<<4);
  *(f16*)(xs + off) = v;
}

// one 64x64x256 wave-GEMM: acc += xs(64x256) @ Wt^T-slice (cols colbase..+64)
// B-fragment loaded inside the n-loop to cap live fragment registers.
__device__ __forceinline__ void gemm256(const unsigned char* xs, const f16* __restrict__ Wt,
                                        int lr, int lg, int colbase,
                                        f32x4 acc[4][4]) {
  for (int kt = 0; kt < 8; ++kt) {
    f16x8 a[4];
    #pragma unroll
    for (int m = 0; m < 4; ++m) a[m] = lda(xs, m, kt, lr, lg);
    #pragma unroll
    for (int n = 0; n < 4; ++n) {
      f16x8 bb = *(const f16x8*)(Wt + (size_t)(colbase + n*16 + lr)*H_ + kt*32 + lg*8);
      #pragma unroll
      for (int m = 0; m < 4; ++m)
        acc[m][n] = __builtin_amdgcn_mfma_f32_16x16x32_f16(a[m], bb, acc[m][n], 0, 0, 0);
    }
  }
}

#define ZERO_ACC(acc)                                                          \
  _Pragma("unroll")                                                            \
  for (int m=0;m<4;++m)                                                        \
    _Pragma("unroll")                                                          \
    for (int n=0;n<4;++n) acc[m][n] = (f32x4)(0.f);

// ---------------- kernel 1: fused GRU + MLP (MFMA fp16) ----------------
// 64 particles per block, 4 waves; wave w owns output cols [w*64, w*64+64).
// Two LDS buffers: xs2 = orig particles (later: nxt), xs = x_reset (later: h1).
// Exactly ONE 64-reg accumulator is live at any time -> no spills.
__global__ __launch_bounds__(256, 2) void k_gru_mlp(
    const float* __restrict__ particles, const float* __restrict__ weights,
    const f16* __restrict__ WrT, const f16* __restrict__ WuT,
    const f16* __restrict__ WcT, const f16* __restrict__ W0T,
    const f16* __restrict__ W1T,
    const float* __restrict__ W2, const float* __restrict__ b1v,
    const float* __restrict__ b2v,
    const float* __restrict__ actR, const float* __restrict__ actU,
    const float* __restrict__ actC, const float* __restrict__ obs0,
    f16* __restrict__ ws_nxt16, float* __restrict__ log_w)
{
  __shared__ __align__(16) unsigned char xs [64*512];  // x_reset -> h1
  __shared__ __align__(16) unsigned char xs2[64*512];  // orig -> nxt
  __shared__ float red[4][64];

  const int b    = blockIdx.x >> 4;
  const int n0   = (blockIdx.x & 15) << 6;
  const int tid  = threadIdx.x;
  const int w    = tid >> 6;
  const int lane = tid & 63;
  const int lr   = lane & 15;
  const int lg   = lane >> 4;
  const int colbase = w << 6;
  const float* Pbase = particles + (size_t)(b*N_ + n0) * H_;

  int colv[4];
  #pragma unroll
  for (int n = 0; n < 4; ++n) colv[n] = colbase + n*16 + lr;

  // ---- stage particles -> xs2 fp16 (swizzled); ONLY global read of P ----
  #pragma unroll
  for (int i = 0; i < 8; ++i) {
    int s = tid + i*256;
    int row = s >> 5, ks = s & 31;
    const float* src = Pbase + row*H_ + ks*8;
    float4 v0 = *(const float4*)src;
    float4 v1 = *(const float4*)(src + 4);
    f16x8 h;
    h[0]=(f16)v0.x; h[1]=(f16)v0.y; h[2]=(f16)v0.z; h[3]=(f16)v0.w;
    h[4]=(f16)v1.x; h[5]=(f16)v1.y; h[6]=(f16)v1.z; h[7]=(f16)v1.w;
    int off = (row*512 + ks*16) ^ ((row&7)<<4);
    *(f16x8*)(xs2 + off) = h;
  }
  __syncthreads();                                  // A: xs2 (orig) ready

  f32x4 acc[4][4];

  // ---- GEMM 1: reset gate; write x_reset = orig * R -> xs ----
  ZERO_ACC(acc);
  gemm256(xs2, WrT, lr, lg, colbase, acc);
  {
    float vR[4];
    #pragma unroll
    for (int n=0;n<4;++n) vR[n] = actR[b*H_ + colv[n]];
    #pragma unroll
    for (int m=0;m<4;++m)
      #pragma unroll
      for (int n=0;n<4;++n)
        #pragma unroll
        for (int r=0;r<4;++r) {
          int row = m*16 + lg*4 + r;
          float Rv = sigm(acc[m][n][r] + vR[n]);
          float o  = (float)xs_r16(xs2, row, colv[n]);
          xs_w16(xs, row, colv[n], (f16)(o * Rv));
        }
  }
  __syncthreads();                                  // B: xs (x_reset) ready

  // ---- GEMM 2: update gate -> uh (packed f16, 32 regs) ----
  ZERO_ACC(acc);
  gemm256(xs2, WuT, lr, lg, colbase, acc);
  f16x4 uh[4][4];
  {
    float vU[4];
    #pragma unroll
    for (int n=0;n<4;++n) vU[n] = actU[b*H_ + colv[n]];
    #pragma unroll
    for (int m=0;m<4;++m)
      #pragma unroll
      for (int n=0;n<4;++n)
        #pragma unroll
        for (int r=0;r<4;++r)
          uh[m][n][r] = (f16)sigm(acc[m][n][r] + vU[n]);
  }

  // ---- GEMM 3: candidate (reads xs) ----
  ZERO_ACC(acc);
  gemm256(xs, WcT, lr, lg, colbase, acc);
  __syncthreads();                                  // C: all GEMM2/3 reads done

  // ---- blend nxt in place into xs2 (each (row,col) owned by one thread) ----
  {
    float vC[4];
    #pragma unroll
    for (int n=0;n<4;++n) vC[n] = actC[b*H_ + colv[n]];
    #pragma unroll
    for (int m=0;m<4;++m)
      #pragma unroll
      for (int n=0;n<4;++n)
        #pragma unroll
        for (int r=0;r<4;++r) {
          int row = m*16 + lg*4 + r;
          float cand = tanhf(acc[m][n][r] + vC[n]);
          float o    = (float)xs_r16(xs2, row, colv[n]);
          float nx   = fmaf((float)uh[m][n][r], cand - o, o);
          xs_w16(xs2, row, colv[n], (f16)nx);
        }
  }
  __syncthreads();                                  // D: xs2 (nxt) ready

  // ---- coalesced nxt (f16) -> global workspace ----
  f16* wsrow = ws_nxt16 + (size_t)(b*N_ + n0) * H_;
  #pragma unroll
  for (int i = 0; i < 8; ++i) {
    int s = tid + i*256;
    int row = s >> 5, c16 = s & 31;
    int off = (row*512 + c16*16) ^ ((row&7)<<4);
    f16x8 v = *(const f16x8*)(xs2 + off);
    *(f16x8*)(wsrow + row*H_ + c16*8) = v;
  }

  // ---- GEMM 4: z @ W0 (nxt part; obs part hoisted) + GELU -> h1 -> xs ----
  ZERO_ACC(acc);
  gemm256(xs2, W0T, lr, lg, colbase, acc);
  {
    float v0b[4];
    #pragma unroll
    for (int n=0;n<4;++n) v0b[n] = obs0[b*H_ + colv[n]];
    #pragma unroll
    for (int m=0;m<4;++m)
      #pragma unroll
      for (int n=0;n<4;++n)
        #pragma unroll
        for (int r=0;r<4;++r)
          xs_w16(xs, m*16 + lg*4 + r, colv[n],
                 (f16)gelu_exact(acc[m][n][r] + v0b[n]));
  }
  __syncthreads();                                  // E: xs (h1) ready

  // ---- GEMM 5: h1 @ W1 + GELU; dot with W2; reduce -> log_lik ----
  ZERO_ACC(acc);
  gemm256(xs, W1T, lr, lg, colbase, acc);

  float v1b[4], w2v[4];
  #pragma unroll
  for (int n=0;n<4;++n) { v1b[n] = b1v[colv[n]]; w2v[n] = W2[colv[n]]; }

  float psum[4][4];   // [m][r]
  #pragma unroll
  for (int m=0;m<4;++m)
    #pragma unroll
    for (int r=0;r<4;++r) psum[m][r] = 0.f;
  #pragma unroll
  for (int m=0;m<4;++m)
    #pragma unroll
    for (int n=0;n<4;++n)
      #pragma unroll
      for (int r=0;r<4;++r)
        psum[m][r] = fmaf(gelu_exact(acc[m][n][r] + v1b[n]), w2v[n], psum[m][r]);

  #pragma unroll
  for (int m=0;m<4;++m)
    #pragma unroll
    for (int r=0;r<4;++r) {
      float v = psum[m][r];
      v += __shfl_xor(v, 1); v += __shfl_xor(v, 2);
      v += __shfl_xor(v, 4); v += __shfl_xor(v, 8);
      psum[m][r] = v;
    }
  if (lr == 0) {
    #pragma unroll
    for (int m=0;m<4;++m)
      #pragma unroll
      for (int r=0;r<4;++r)
        red[w][m*16 + lg*4 + r] = psum[m][r];
  }
  __syncthreads();                                  // F: red ready
  if (tid < 64) {
    float ll = red[0][tid] + red[1][tid] + red[2][tid] + red[3][tid] + b2v[0];
    int gi = b*N_ + n0 + tid;
    log_w[gi] = logf(weights[gi] + EPSF) + ll;
  }
}

// ---------------- kernel 2: per-batch softmax / ESS / csum / searchsorted ----
__global__ __launch_bounds__(256) void k_softmax(
    const float* __restrict__ log_w, const float* __restrict__ u_in,
    float* __restrict__ d_new_w, float* __restrict__ d_ess,
    int* __restrict__ ws_idx, float* __restrict__ ws_should)
{
  __shared__ float cs[N_];
  __shared__ float redbuf[4];
  __shared__ float wsum[4];
  const int b = blockIdx.x, t = threadIdx.x;
  const int wave = t >> 6, lane = t & 63;
  const float* lw = log_w + b*N_;

  float v[4];
  float m = -INFINITY;
  #pragma unroll
  for (int q = 0; q < 4; ++q) { v[q] = lw[t*4+q]; m = fmaxf(m, v[q]); }
  for (int off = 32; off >= 1; off >>= 1) m = fmaxf(m, __shfl_xor(m, off));
  if (lane == 0) redbuf[wave] = m;
  __syncthreads();
  m = fmaxf(fmaxf(redbuf[0], redbuf[1]), fmaxf(redbuf[2], redbuf[3]));

  float s4 = 0.f;
  #pragma unroll
  for (int q = 0; q < 4; ++q) { v[q] = expf(v[q] - m); s4 += v[q]; }

  // wave-level inclusive scan of per-thread sums
  float incl = s4;
  #pragma unroll
  for (int off = 1; off < 64; off <<= 1) {
    float t2 = __shfl_up(incl, off);
    if (lane >= off) incl += t2;
  }
  if (lane == 63) wsum[wave] = incl;
  __syncthreads();
  float woff = 0.f;
  #pragma unroll
  for (int ww = 0; ww < 4; ++ww) woff += (ww < wave) ? wsum[ww] : 0.f;
  const float total = wsum[0] + wsum[1] + wsum[2] + wsum[3];
  const float excl  = woff + incl - s4;
  const float inv   = 1.0f / total;

  float run = excl, sq4 = 0.f;
  #pragma unroll
  for (int q = 0; q < 4; ++q) {
    run += v[q];
    cs[t*4+q] = run * inv;
    float wq = v[q] * inv;
    sq4 += wq * wq;
  }
  for (int off = 32; off >= 1; off >>= 1) sq4 += __shfl_xor(sq4, off);
  __syncthreads();          // cs fully written (also covers redbuf reuse)
  if (lane == 0) redbuf[wave] = sq4;
  __syncthreads();
  const float ssq = redbuf[0] + redbuf[1] + redbuf[2] + redbuf[3];
  const float ess = 1.0f / (ssq + EPSF);
  const bool should = ess < (0.5f * (float)N_);
  if (t == 0) { d_ess[b] = ess; ws_should[b] = should ? 1.0f : 0.0f; }

  const float uw = 1.0f / (float)N_;
  #pragma unroll
  for (int q = 0; q < 4; ++q)
    d_new_w[b*N_ + t*4+q] = should ? uw : v[q] * inv;

  const float ub = u_in[b];
  #pragma unroll
  for (int q = 0; q < 4; ++q) {
    int i = t*4 + q;
    float pos = fminf(ub / (float)N_ + (float)i / (float)N_, 0.9999f);
    int lo = 0, hi = N_;
    while (lo < hi) { int mid = (lo + hi) >> 1; if (cs[mid] < pos) lo = mid + 1; else hi = mid; }
    ws_idx[b*N_ + i] = (lo < N_-1) ? lo : N_-1;
  }
}

// ---------------- kernel 3: resample-select + belief ----------------
// block: 64 rows of one batch; thread t: col-pair (t&127), row-half (t>>7)
__global__ __launch_bounds__(256) void k_final(
    const f16* __restrict__ ws_nxt16, const int* __restrict__ ws_idx,
    const float* __restrict__ ws_should, const float* __restrict__ d_new_w,
    float* __restrict__ d_nxt, float* __restrict__ d_belief)
{
  const int blk = blockIdx.x;
  const int b   = blk >> 4;
  const int n0  = (blk & 15) << 6;
  const int t   = threadIdx.x;
  const int c   = t & 127;          // col pair
  const int hf  = t >> 7;           // row half
  const bool should = ws_should[b] != 0.0f;
  float p0 = 0.f, p1 = 0.f;
  #pragma unroll 4
  for (int r = 0; r < 32; ++r) {
    int n = n0 + hf*32 + r;
    int src = should ? ws_idx[b*N_ + n] : n;
    f16x2 v = *(const f16x2*)(ws_nxt16 + (size_t)(b*N_ + src)*H_ + c*2);
    float w = d_new_w[b*N_ + n];
    float2 st; st.x = (float)v[0]; st.y = (float)v[1];
    *(float2*)(d_nxt + (size_t)(b*N_ + n)*H_ + c*2) = st;
    p0 = fmaf(st.x, w, p0); p1 = fmaf(st.y, w, p1);
  }
  atomicAdd(&d_belief[b*H_ + c*2],     p0);
  atomicAdd(&d_belief[b*H_ + c*2 + 1], p1);
}

// ---------------- launch ----------------
extern "C" void kernel_launch(void* const* d_in, const int* in_sizes, int n_in,
                              void* d_out, int out_size, void* d_ws, size_t ws_size,
                              hipStream_t stream) {
  (void)in_sizes; (void)n_in; (void)out_size; (void)ws_size;
  const float* particles   = (const float*)d_in[0];
  const float* weights     = (const float*)d_in[1];
  const float* action      = (const float*)d_in[2];
  const float* observation = (const float*)d_in[3];
  const float* u_in        = (const float*)d_in[4];
  const float* Wr = (const float*)d_in[5];
  const float* br = (const float*)d_in[6];
  const float* Wu = (const float*)d_in[7];
  const float* bu = (const float*)d_in[8];
  const float* Wc = (const float*)d_in[9];
  const float* bc = (const float*)d_in[10];
  const float* W0 = (const float*)d_in[11];
  const float* b0 = (const float*)d_in[12];
  const float* W1 = (const float*)d_in[13];
  const float* b1 = (const float*)d_in[14];
  const float* W2 = (const float*)d_in[15];
  const float* b2 = (const float*)d_in[16];

  float* out      = (float*)d_out;
  float* d_belief = out;                                  // [B,H]
  float* d_nxt    = out + (size_t)B_*H_;                  // [B,N,H]
  float* d_new_w  = d_nxt + (size_t)M_*H_;                // [B,N]
  float* d_ess    = d_new_w + M_;                         // [B]

  unsigned char* wsb = (unsigned char*)d_ws;
  f16* WrT = (f16*)wsb;                                   // 5 x 256x256 fp16
  f16* WuT = WrT + H_*H_;
  f16* WcT = WuT + H_*H_;
  f16* W0T = WcT + H_*H_;
  f16* W1T = W0T + H_*H_;
  f16* ws_nxt16   = W1T + H_*H_;                          // [M,H] f16, 16 MB
  float* ws_logw  = (float*)(ws_nxt16 + (size_t)M_*H_);   // [M]
  float* ws_actR  = ws_logw + M_;                         // [B,H] x4
  float* ws_actU  = ws_actR + B_*H_;
  float* ws_actC  = ws_actU + B_*H_;
  float* ws_obs0  = ws_actC + B_*H_;
  int*   ws_idx   = (int*)(ws_obs0 + B_*H_);              // [B,N]
  float* ws_should= (float*)(ws_idx + M_);                // [B]

  hipMemsetAsync(d_belief, 0, (size_t)B_*H_*sizeof(float), stream);

  k_prep<<<dim3(112), dim3(256), 0, stream>>>(
      action, observation, Wr, br, Wu, bu, Wc, bc, W0, b0,
      WrT, WuT, WcT, W0T, W1T, W1,
      ws_actR, ws_actU, ws_actC, ws_obs0);

  k_gru_mlp<<<dim3(M_/64), dim3(256), 0, stream>>>(
      particles, weights, WrT, WuT, WcT, W0T, W1T, W2, b1, b2,
      ws_actR, ws_actU, ws_actC, ws_obs0, ws_nxt16, ws_logw);

  k_softmax<<<dim3(B_), dim3(256), 0, stream>>>(
      ws_logw, u_in, d_new_w, d_ess, ws_idx, ws_should);

  k_final<<<dim3(M_/64), dim3(256), 0, stream>>>(
      ws_nxt16, ws_idx, ws_should, d_new_w, d_nxt, d_belief);
}